// Round 1
// 283.371 us; speedup vs baseline: 1.0909x; 1.0909x over previous
//
#include <hip/hip_runtime.h>
#include <math.h>

// Shape fixed by reference: x, identity: [8,4096,768] f32; scales [768] f32.
static constexpr int kD = 768;
static constexpr int kRows = 32768;
static constexpr long long kN = (long long)kRows * kD;  // 25165824
static constexpr int kColGroups = 192;                  // float4s per row (3 KB)
static constexpr int kBlocks = 2048;
static constexpr int kRowsPerBlock = 16;                // 16 rows x 3KB = 48KB/block

typedef float nf4 __attribute__((ext_vector_type(4)));

// Layout: 192-thread blocks (3 waves). threadIdx.x IS the f4-column, so each
// wave reads a contiguous 1KB line per instruction and the per-thread column
// (and its dyadic factors) is loop-invariant. Each block sweeps 16 contiguous
// rows (48KB contiguous footprint). XCD swizzle unchanged from prior session
// (held as control this round).
__device__ __forceinline__ int swizzled_block() {
    return (int)((blockIdx.x & 7) * (kBlocks >> 3) + (blockIdx.x >> 3));
}

// ---------------------------------------------------------------------------
// Pass 1: per-block partial amax of |x + identity|.
// R5 change: NO atomics. 6144 same-address device atomicMax ops serialized at
// ~16 ns each == the entire 100 us kernel duration. Replace with LDS cross-wave
// reduce -> one plain f32 store per block into ws partial array.
// ---------------------------------------------------------------------------
__global__ __launch_bounds__(192, 4) void amax_kernel(
    const float4* __restrict__ x, const float4* __restrict__ idn,
    float* __restrict__ partial)
{
    const int b = swizzled_block();
    const int t = threadIdx.x;  // f4-column 0..191
    const int base = b * (kRowsPerBlock * kColGroups) + t;

    float4 m4 = make_float4(0.f, 0.f, 0.f, 0.f);
    #pragma unroll 1
    for (int outer = 0; outer < 4; ++outer) {
        const int rb = base + outer * 4 * kColGroups;
        float4 a[4], c[4];
        #pragma unroll
        for (int j = 0; j < 4; ++j) a[j] = x[rb + j * kColGroups];
        #pragma unroll
        for (int j = 0; j < 4; ++j) c[j] = idn[rb + j * kColGroups];
        __builtin_amdgcn_sched_barrier(0);  // keep all 8 loads in flight
        #pragma unroll
        for (int j = 0; j < 4; ++j) {
            m4.x = fmaxf(m4.x, fabsf(a[j].x + c[j].x));
            m4.y = fmaxf(m4.y, fabsf(a[j].y + c[j].y));
            m4.z = fmaxf(m4.z, fabsf(a[j].z + c[j].z));
            m4.w = fmaxf(m4.w, fabsf(a[j].w + c[j].w));
        }
        __builtin_amdgcn_sched_barrier(0);
    }
    float m = fmaxf(fmaxf(m4.x, m4.y), fmaxf(m4.z, m4.w));
    #pragma unroll
    for (int off = 32; off > 0; off >>= 1)
        m = fmaxf(m, __shfl_down(m, off, 64));

    __shared__ float wmax[3];
    if ((t & 63) == 0) wmax[t >> 6] = m;
    __syncthreads();
    if (t == 0)
        partial[blockIdx.x] = fmaxf(fmaxf(wmax[0], wmax[1]), wmax[2]);
}

// Dyadic multiplier matching _batch_frexp exactly:
//   m, e = frexp(r); m_int = floor(m*2^31 + 0.5); factor = m_int * 2^(e-31)
__device__ inline double quant_factor(double r) {
    int e;
    double mm = frexp(r, &e);
    double m_int = floor(mm * 2147483648.0 + 0.5);
    return ldexp(m_int, e - 31);
}

// ---------------------------------------------------------------------------
// Pass 1.5: single block. Reduce 2048 partial maxes -> z_scale; then the
// per-column dyadic factors (768 of each) + z_scale outputs.
// ---------------------------------------------------------------------------
__global__ __launch_bounds__(768) void factor_kernel(
    const float* __restrict__ pre, const float* __restrict__ ids,
    const float* __restrict__ partial,
    double* __restrict__ fp, double* __restrict__ fi,
    float* __restrict__ z_scale_ws, float* __restrict__ out_scale)
{
    const int t = threadIdx.x;

    float m = 0.f;
    #pragma unroll
    for (int i = t; i < kBlocks; i += 768) m = fmaxf(m, partial[i]);
    #pragma unroll
    for (int off = 32; off > 0; off >>= 1)
        m = fmaxf(m, __shfl_down(m, off, 64));

    __shared__ float wmax[12];
    __shared__ float zs_sh;
    if ((t & 63) == 0) wmax[t >> 6] = m;
    __syncthreads();
    if (t == 0) {
        float mm = wmax[0];
        #pragma unroll
        for (int w = 1; w < 12; ++w) mm = fmaxf(mm, wmax[w]);
        // identical f32 arithmetic to reference: max(amax/127, eps)
        float zs = fmaxf(mm / 127.0f, 1.1920928955078125e-07f);
        zs_sh = zs;
        *z_scale_ws = zs;
        *out_scale = zs;
    }
    __syncthreads();

    const double zsd = (double)zs_sh;
    if (t < kD) {
        fp[t] = quant_factor((double)pre[t] / zsd);
        fi[t] = quant_factor((double)ids[t] / zsd);
    }
}

__device__ inline float requant_elem(float xx, float ii, float p, float s,
                                     double fp, double fi, float z_scale) {
    float z_int = rintf(xx / p);            // IEEE f32 div + half-even, as ref
    float w_int = rintf(ii / s);
    double o  = rint((double)z_int * fp);   // exact f64 product (<= 44 bits)
    double o1 = rint((double)w_int * fi);
    float q = (float)(o + o1);
    q = fminf(fmaxf(q, -128.0f), 127.0f);
    return q * z_scale;
}

// ---------------------------------------------------------------------------
// Pass 2: elementwise requantize, same row-sweep layout (unchanged control).
// Column (= factors) loop-invariant per thread; nt stores (never re-read).
// ---------------------------------------------------------------------------
__global__ __launch_bounds__(192, 4) void quant_kernel(
    const float4* __restrict__ x, const float4* __restrict__ idn,
    const float4* __restrict__ pre, const float4* __restrict__ ids,
    const float* __restrict__ z_scale_ws,
    const double* __restrict__ fp_tab, const double* __restrict__ fi_tab,
    nf4* __restrict__ out)
{
    const float z_scale = *z_scale_ws;

    const int b = swizzled_block();
    const int t = threadIdx.x;  // f4-column = column group
    const int base = b * (kRowsPerBlock * kColGroups) + t;

    const float4 pf = pre[t];
    const float4 sf = ids[t];
    double fp[4], fi[4];
    #pragma unroll
    for (int j = 0; j < 4; ++j) { fp[j] = fp_tab[4*t + j]; fi[j] = fi_tab[4*t + j]; }

    #pragma unroll 1
    for (int outer = 0; outer < 4; ++outer) {
        const int rb = base + outer * 4 * kColGroups;
        float4 xa[4], ia[4];
        #pragma unroll
        for (int j = 0; j < 4; ++j) xa[j] = x[rb + j * kColGroups];
        #pragma unroll
        for (int j = 0; j < 4; ++j) ia[j] = idn[rb + j * kColGroups];
        __builtin_amdgcn_sched_barrier(0);  // keep all 8 loads in flight
        #pragma unroll
        for (int j = 0; j < 4; ++j) {
            nf4 ov;
            ov.x = requant_elem(xa[j].x, ia[j].x, pf.x, sf.x, fp[0], fi[0], z_scale);
            ov.y = requant_elem(xa[j].y, ia[j].y, pf.y, sf.y, fp[1], fi[1], z_scale);
            ov.z = requant_elem(xa[j].z, ia[j].z, pf.z, sf.z, fp[2], fi[2], z_scale);
            ov.w = requant_elem(xa[j].w, ia[j].w, pf.w, sf.w, fp[3], fi[3], z_scale);
            __builtin_nontemporal_store(ov, &out[rb + j * kColGroups]);
        }
        __builtin_amdgcn_sched_barrier(0);
    }
}

extern "C" void kernel_launch(void* const* d_in, const int* in_sizes, int n_in,
                              void* d_out, int out_size, void* d_ws, size_t ws_size,
                              hipStream_t stream) {
    const float* x   = (const float*)d_in[0];
    const float* pre = (const float*)d_in[1];
    const float* idn = (const float*)d_in[2];
    const float* ids = (const float*)d_in[3];
    float* out = (float*)d_out;

    // ws layout: [0,4) z_scale; [64, 64+8192) per-block partial maxes;
    // then fp table (768 f64), fi table (768 f64). Every word rewritten each
    // launch -> no memset needed, re-poison safe.
    float* z_scale_ws = (float*)d_ws;
    float* partial = (float*)((char*)d_ws + 64);
    double* fp_tab = (double*)((char*)d_ws + 64 + kBlocks * sizeof(float));
    double* fi_tab = fp_tab + kD;

    amax_kernel<<<kBlocks, 192, 0, stream>>>(
        (const float4*)x, (const float4*)idn, partial);
    factor_kernel<<<1, 768, 0, stream>>>(pre, ids, partial, fp_tab, fi_tab,
                                         z_scale_ws, out + kN);
    quant_kernel<<<kBlocks, 192, 0, stream>>>(
        (const float4*)x, (const float4*)idn,
        (const float4*)pre, (const float4*)ids,
        z_scale_ws, fp_tab, fi_tab, (nf4*)out);
}

// Round 2
// 281.121 us; speedup vs baseline: 1.0996x; 1.0080x over previous
//
#include <hip/hip_runtime.h>
#include <math.h>

// Shape fixed by reference: x, identity: [8,4096,768] f32; scales [768] f32.
static constexpr int kD = 768;
static constexpr int kRows = 32768;
static constexpr long long kN = (long long)kRows * kD;  // 25165824
static constexpr int kColGroups = 192;                  // float4s per row (3 KB)

// R6 layout: oversubscribed grids (4096 blocks) so block count no longer caps
// resident waves; small VGPR footprints so 8 waves/SIMD are possible; no
// sched_barrier drains (let compiler keep loads in flight through compute).
static constexpr int kAmaxBlocks = 4096;   // 256 thr: wave-linear 6KB chunks
static constexpr int kQuantBlocks = 4096;  // 192 thr: 8 rows/block
static constexpr int kQuantRows = 8;

typedef float nf4 __attribute__((ext_vector_type(4)));

__device__ __forceinline__ int swz(int bid, int nblk) {
    // bijective XCD regroup (nblk % 8 == 0): each XCD sweeps contiguous 1/8.
    return (bid & 7) * (nblk >> 3) + (bid >> 3);
}

// ---------------------------------------------------------------------------
// Pass 1: per-block partial amax of |x + identity|.
// Each WAVE owns a contiguous 6KB chunk of x (and the matching idn chunk):
// lane addr = chunk + k*1KB + lane*16B, k=0..5. Two batches of 6 loads
// (3 x-f4 + 3 idn-f4) keep ~6 loads in flight per wave at ~48 data VGPRs,
// leaving room for 8 waves/SIMD. Grid 4096 x 4 waves = 16384 chunks.
// ---------------------------------------------------------------------------
__global__ __launch_bounds__(256) void amax_kernel(
    const float4* __restrict__ x, const float4* __restrict__ idn,
    float* __restrict__ partial)
{
    const int b = swz((int)blockIdx.x, kAmaxBlocks);
    const int wave = threadIdx.x >> 6;
    const int lane = threadIdx.x & 63;
    const int base = (b * 4 + wave) * 384 + lane;  // f4 units; max < 6.3M

    float4 m4 = make_float4(0.f, 0.f, 0.f, 0.f);
    #pragma unroll
    for (int half = 0; half < 2; ++half) {
        const int o = base + half * 192;
        float4 a[3], c[3];
        #pragma unroll
        for (int j = 0; j < 3; ++j) a[j] = x[o + j * 64];
        #pragma unroll
        for (int j = 0; j < 3; ++j) c[j] = idn[o + j * 64];
        #pragma unroll
        for (int j = 0; j < 3; ++j) {
            m4.x = fmaxf(m4.x, fabsf(a[j].x + c[j].x));
            m4.y = fmaxf(m4.y, fabsf(a[j].y + c[j].y));
            m4.z = fmaxf(m4.z, fabsf(a[j].z + c[j].z));
            m4.w = fmaxf(m4.w, fabsf(a[j].w + c[j].w));
        }
    }
    float m = fmaxf(fmaxf(m4.x, m4.y), fmaxf(m4.z, m4.w));
    #pragma unroll
    for (int off = 32; off > 0; off >>= 1)
        m = fmaxf(m, __shfl_down(m, off, 64));

    __shared__ float wmax[4];
    if (lane == 0) wmax[wave] = m;
    __syncthreads();
    if (threadIdx.x == 0)
        partial[blockIdx.x] =
            fmaxf(fmaxf(wmax[0], wmax[1]), fmaxf(wmax[2], wmax[3]));
}

// Dyadic multiplier matching _batch_frexp exactly:
//   m, e = frexp(r); m_int = floor(m*2^31 + 0.5); factor = m_int * 2^(e-31)
__device__ inline double quant_factor(double r) {
    int e;
    double mm = frexp(r, &e);
    double m_int = floor(mm * 2147483648.0 + 0.5);
    return ldexp(m_int, e - 31);
}

// ---------------------------------------------------------------------------
// Pass 1.5: single block. Reduce 4096 partial maxes -> z_scale; then the
// per-column dyadic factors (768 of each) + z_scale outputs.
// ---------------------------------------------------------------------------
__global__ __launch_bounds__(768) void factor_kernel(
    const float* __restrict__ pre, const float* __restrict__ ids,
    const float* __restrict__ partial,
    double* __restrict__ fp, double* __restrict__ fi,
    float* __restrict__ z_scale_ws, float* __restrict__ out_scale)
{
    const int t = threadIdx.x;

    float m = 0.f;
    #pragma unroll
    for (int i = t; i < kAmaxBlocks; i += 768) m = fmaxf(m, partial[i]);
    #pragma unroll
    for (int off = 32; off > 0; off >>= 1)
        m = fmaxf(m, __shfl_down(m, off, 64));

    __shared__ float wmax[12];
    __shared__ float zs_sh;
    if ((t & 63) == 0) wmax[t >> 6] = m;
    __syncthreads();
    if (t == 0) {
        float mm = wmax[0];
        #pragma unroll
        for (int w = 1; w < 12; ++w) mm = fmaxf(mm, wmax[w]);
        // identical f32 arithmetic to reference: max(amax/127, eps)
        float zs = fmaxf(mm / 127.0f, 1.1920928955078125e-07f);
        zs_sh = zs;
        *z_scale_ws = zs;
        *out_scale = zs;
    }
    __syncthreads();

    const double zsd = (double)zs_sh;
    if (t < kD) {
        fp[t] = quant_factor((double)pre[t] / zsd);
        fi[t] = quant_factor((double)ids[t] / zsd);
    }
}

__device__ inline float requant_elem(float xx, float ii, float p, float s,
                                     double fp, double fi, float z_scale) {
    float z_int = rintf(xx / p);            // IEEE f32 div + half-even, as ref
    float w_int = rintf(ii / s);
    double o  = rint((double)z_int * fp);   // exact f64 product (<= 44 bits)
    double o1 = rint((double)w_int * fi);
    float q = (float)(o + o1);
    q = fminf(fmaxf(q, -128.0f), 127.0f);
    return q * z_scale;
}

// ---------------------------------------------------------------------------
// Pass 2: elementwise requantize. 192-thread blocks keep threadIdx.x == the
// f4-column, so per-thread factors stay loop-invariant in registers. Grid
// 4096 (8 rows/block) removes the block-count occupancy cap; rows processed
// in batches of 3 (6 f4 in flight = 24 data VGPRs) to stay under the 64-VGPR
// occupancy step.
// ---------------------------------------------------------------------------
template <int R>
__device__ __forceinline__ void quant_rows(
    const float4* __restrict__ x, const float4* __restrict__ idn,
    nf4* __restrict__ out, int rb,
    const float4& pf, const float4& sf,
    const double* fp, const double* fi, float z_scale)
{
    float4 xa[R], ia[R];
    #pragma unroll
    for (int j = 0; j < R; ++j) xa[j] = x[rb + j * kColGroups];
    #pragma unroll
    for (int j = 0; j < R; ++j) ia[j] = idn[rb + j * kColGroups];
    #pragma unroll
    for (int j = 0; j < R; ++j) {
        nf4 ov;
        ov.x = requant_elem(xa[j].x, ia[j].x, pf.x, sf.x, fp[0], fi[0], z_scale);
        ov.y = requant_elem(xa[j].y, ia[j].y, pf.y, sf.y, fp[1], fi[1], z_scale);
        ov.z = requant_elem(xa[j].z, ia[j].z, pf.z, sf.z, fp[2], fi[2], z_scale);
        ov.w = requant_elem(xa[j].w, ia[j].w, pf.w, sf.w, fp[3], fi[3], z_scale);
        __builtin_nontemporal_store(ov, &out[rb + j * kColGroups]);
    }
}

__global__ __launch_bounds__(192) void quant_kernel(
    const float4* __restrict__ x, const float4* __restrict__ idn,
    const float4* __restrict__ pre, const float4* __restrict__ ids,
    const float* __restrict__ z_scale_ws,
    const double* __restrict__ fp_tab, const double* __restrict__ fi_tab,
    nf4* __restrict__ out)
{
    const float z_scale = *z_scale_ws;

    const int b = swz((int)blockIdx.x, kQuantBlocks);
    const int t = threadIdx.x;  // f4-column = column group
    const int base = b * (kQuantRows * kColGroups) + t;

    const float4 pf = pre[t];
    const float4 sf = ids[t];
    double fp[4], fi[4];
    #pragma unroll
    for (int j = 0; j < 4; ++j) { fp[j] = fp_tab[4*t + j]; fi[j] = fi_tab[4*t + j]; }

    quant_rows<3>(x, idn, out, base + 0 * kColGroups, pf, sf, fp, fi, z_scale);
    quant_rows<3>(x, idn, out, base + 3 * kColGroups, pf, sf, fp, fi, z_scale);
    quant_rows<2>(x, idn, out, base + 6 * kColGroups, pf, sf, fp, fi, z_scale);
}

extern "C" void kernel_launch(void* const* d_in, const int* in_sizes, int n_in,
                              void* d_out, int out_size, void* d_ws, size_t ws_size,
                              hipStream_t stream) {
    const float* x   = (const float*)d_in[0];
    const float* pre = (const float*)d_in[1];
    const float* idn = (const float*)d_in[2];
    const float* ids = (const float*)d_in[3];
    float* out = (float*)d_out;

    // ws layout: [0,4) z_scale; [64, 64+16384) per-block partial maxes;
    // then fp table (768 f64), fi table (768 f64). Every word rewritten each
    // launch -> no memset needed, re-poison safe.
    float* z_scale_ws = (float*)d_ws;
    float* partial = (float*)((char*)d_ws + 64);
    double* fp_tab = (double*)((char*)d_ws + 64 + kAmaxBlocks * sizeof(float));
    double* fi_tab = fp_tab + kD;

    amax_kernel<<<kAmaxBlocks, 256, 0, stream>>>(
        (const float4*)x, (const float4*)idn, partial);
    factor_kernel<<<1, 768, 0, stream>>>(pre, ids, partial, fp_tab, fi_tab,
                                         z_scale_ws, out + kN);
    quant_kernel<<<kQuantBlocks, 192, 0, stream>>>(
        (const float4*)x, (const float4*)idn,
        (const float4*)pre, (const float4*)ids,
        z_scale_ws, fp_tab, fi_tab, (nf4*)out);
}